// Round 5
// baseline (1606.556 us; speedup 1.0000x reference)
//
#include <hip/hip_runtime.h>

typedef _Float16 f16;
typedef _Float16 half8 __attribute__((ext_vector_type(8)));
typedef float floatx4 __attribute__((ext_vector_type(4)));
typedef unsigned long long u64;
typedef unsigned int u32;

// Problem sizes
#define NB 64
#define NS 256
#define NE 512
#define NH 512
#define NG 2048   // 4H
#define NN 4096   // 2 dirs * 4H

// ---------------- workspace layout (bytes) ----------------
// xp     : f16 [16384][4096]   134217728   gate preacts (bias folded), both dirs
// emb_h  : f16 [16384][512]     16777216   (first 512KB reused as h_ex by k_rec,
//                                          which runs strictly after k_gemm)
// w_cat  : f16 [4096][512]       4194304   [w_ih_f ; w_ih_b]
// whh    : f16 [2][2048][512]    4194304
// h_seq  : f16 [64][256][1024]  33554432   [h_f | h_b] for attention
// h_ex   : u64 [2par][8gid][16jg][256u]    524288  tagged-h exchange (in emb_h region)
// bias   : f32 [4096]              16384
#define OFF_XP     0
#define OFF_EMB    134217728
#define OFF_HEX    134217728   // aliases emb_h: dead after k_gemm, k_rec is stream-ordered after
#define OFF_WCAT   150994944
#define OFF_WHH    155189248
#define OFF_HSEQ   159383552
#define OFF_BIAS   193200128

__device__ __forceinline__ void cbar() {  // compiler-only reorder barrier
  asm volatile("" ::: "memory");
}

// ---------------- prep: combine biases ----------------
__global__ void k_prep(float* bias, const float* bihf, const float* bhhf,
                       const float* bihb, const float* bhhb) {
  int id = blockIdx.x * 256 + threadIdx.x;       // 4096 threads
  bias[id] = (id < 2048) ? (bihf[id] + bhhf[id]) : (bihb[id - 2048] + bhhb[id - 2048]);
}

// ---------------- embedding gather + f32->f16 cast ----------------
__global__ void k_embed(const int* __restrict__ x, const float* __restrict__ embed,
                        f16* __restrict__ emb_h) {
  int gid = blockIdx.x * 256 + threadIdx.x;      // 1048576 threads, 8 halves each
  size_t base = (size_t)gid * 8;
  int r = (int)(base >> 9);
  int e = (int)(base & 511);
  int xi = x[r];
  const float4* src = (const float4*)(embed + (size_t)xi * 512 + e);
  float4 a = src[0], b = src[1];
  half8 h;
  h[0] = (f16)a.x; h[1] = (f16)a.y; h[2] = (f16)a.z; h[3] = (f16)a.w;
  h[4] = (f16)b.x; h[5] = (f16)b.y; h[6] = (f16)b.z; h[7] = (f16)b.w;
  *(half8*)(emb_h + base) = h;
}

// ---------------- weight casts ----------------
__global__ void k_wcast(const float* __restrict__ wihf, const float* __restrict__ wihb,
                        const float* __restrict__ whhf, const float* __restrict__ whhb,
                        f16* __restrict__ w_cat, f16* __restrict__ whh) {
  int gid = blockIdx.x * 256 + threadIdx.x;      // 524288 threads, 8 halves each
  size_t i8 = (size_t)gid * 8;
  const float* src;
  f16* dst;
  if (i8 < 2097152) {                            // w_cat [4096][512]
    size_t n = i8 >> 9, k = i8 & 511;
    src = (n < 2048 ? wihf + n * 512 : wihb + (n - 2048) * 512) + k;
    dst = w_cat + i8;
  } else {                                       // whh [2][2048][512]
    size_t i2 = i8 - 2097152;
    int dir = (int)(i2 >> 20);
    size_t rk = i2 & 1048575;
    src = (dir ? whhb : whhf) + rk;
    dst = whh + i2;
  }
  float4 a = *(const float4*)src, b = *(const float4*)(src + 4);
  half8 h;
  h[0] = (f16)a.x; h[1] = (f16)a.y; h[2] = (f16)a.z; h[3] = (f16)a.w;
  h[4] = (f16)b.x; h[5] = (f16)b.y; h[6] = (f16)b.z; h[7] = (f16)b.w;
  *(half8*)dst = h;
}

// ---------------- xproj GEMM: [16384,512] @ [4096,512]^T -> f16, +bias ----------
// Round-2 proven version (plain uint4 staging; k_gemm is not the bottleneck).
__global__ __launch_bounds__(256) void k_gemm(const f16* __restrict__ A,
                                              const f16* __restrict__ Bw,
                                              const float* __restrict__ bias,
                                              f16* __restrict__ xp) {
  __shared__ __align__(16) f16 As[128 * 32];
  __shared__ __align__(16) f16 Bs[128 * 32];
  const int t = threadIdx.x;
  const int m0 = blockIdx.x * 128;
  const int n0 = blockIdx.y * 128;
  const int w = t >> 6, l = t & 63;
  const int wm = w >> 1, wn = w & 1;
  const int l15 = l & 15, q8 = (l >> 4) * 8;

  floatx4 acc[4][4];
#pragma unroll
  for (int mi = 0; mi < 4; mi++)
#pragma unroll
    for (int ni = 0; ni < 4; ni++) {
      acc[mi][ni][0] = 0.f; acc[mi][ni][1] = 0.f;
      acc[mi][ni][2] = 0.f; acc[mi][ni][3] = 0.f;
    }

  for (int kt = 0; kt < 16; kt++) {
#pragma unroll
    for (int i = 0; i < 2; i++) {
      int c = t + 256 * i;
      int row = c >> 2, kc = (c & 3) * 8;
      *(uint4*)&As[row * 32 + kc] = *(const uint4*)(A + (size_t)(m0 + row) * 512 + kt * 32 + kc);
      *(uint4*)&Bs[row * 32 + kc] = *(const uint4*)(Bw + (size_t)(n0 + row) * 512 + kt * 32 + kc);
    }
    __syncthreads();
    half8 af[4], bf[4];
#pragma unroll
    for (int mi = 0; mi < 4; mi++)
      af[mi] = *(const half8*)&As[(wm * 64 + mi * 16 + l15) * 32 + q8];
#pragma unroll
    for (int ni = 0; ni < 4; ni++)
      bf[ni] = *(const half8*)&Bs[(wn * 64 + ni * 16 + l15) * 32 + q8];
#pragma unroll
    for (int mi = 0; mi < 4; mi++)
#pragma unroll
      for (int ni = 0; ni < 4; ni++)
        acc[mi][ni] = __builtin_amdgcn_mfma_f32_16x16x32_f16(af[mi], bf[ni], acc[mi][ni], 0, 0, 0);
    __syncthreads();
  }

#pragma unroll
  for (int ni = 0; ni < 4; ni++) {
    int ng = n0 + wn * 64 + ni * 16 + l15;
    float bv = bias[ng];
#pragma unroll
    for (int mi = 0; mi < 4; mi++) {
      int mg = m0 + wm * 64 + mi * 16 + (l >> 4) * 4;
#pragma unroll
      for (int r = 0; r < 4; r++)
        xp[(size_t)(mg + r) * 4096 + ng] = (f16)(acc[mi][ni][r] + bv);
    }
  }
}

// ---------------- recurrent kernel ----------------
// 128 blocks: blk = gid + 8*jg; gid = dir*4+bg (8 independent sync groups of 16
// blocks). Group handles 16 batches of one direction; block jg owns 32 hidden
// units; wave w owns gate type w (i,f,g,o); w_hh rows live in VGPRs (fa).
//
// Sync protocol (system-scope only, flag-free, deadlock-free):
// h is exchanged as TAGGED u64 units: [u32 tag = step | f16 h_{2p} | f16 h_{2p+1}].
// Tag and data are atomic within one 8-byte store, so no release ack and no
// separate flag round-trip exist. Producers fire-and-forget 256 u64/step into
// the double-buffered slab; consumers retry-load their 16 u64s until every tag
// equals the current step. Monotonic tags + double buffer + (skew<=1 proof:
// a block enters step st only after observing all peers' step-st tags, which
// are stored after those peers' slab reads) make overwrites safe. 0xAA poison
// never matches a tag in [1,256]; h_ex is never read before written (st=0
// skips the h-MFMA since h==0), so no initialization is needed.
__global__ __launch_bounds__(256, 1) void k_rec(const f16* __restrict__ whh,
                                                const f16* __restrict__ xp,
                                                u64* __restrict__ h_ex,
                                                f16* __restrict__ h_seq) {
  const int blk = blockIdx.x;
  const int gid = blk & 7;
  const int dir = gid >> 2, bg = gid & 3;
  const int jg  = blk >> 3;
  const int t = threadIdx.x;
  const int w = t >> 6, l = t & 63;
  const int l15 = l & 15, q = l >> 4;

  // A-frags: 32 w_hh rows per wave (2 m-tiles of 16), resident whole kernel
  half8 fa[2][16];
  {
    const f16* wb = whh + ((size_t)dir * 2048 + w * 512 + jg * 32 + l15) * 512;
#pragma unroll
    for (int mi = 0; mi < 2; mi++)
#pragma unroll
      for (int kt = 0; kt < 16; kt++)
        fa[mi][kt] = *(const half8*)(wb + (size_t)mi * 16 * 512 + kt * 32 + q * 8);
  }

  __shared__ __align__(16) f16 hbuf[16 * 640];   // [kt][b16][40]: 80B rows = 5x16B -> conflict-free b128
  __shared__ float zbuf[4][32][17];              // [gate][hu_local][b16 pad17]
  __shared__ __align__(16) f16 hstage[16][32];   // [b][hu_local]

  float creg[2] = {0.f, 0.f};
  const int uhu = t & 31, ub = t >> 5;           // cell update: hu, batches ub and ub+8

  // xp: row=(16bg+l15)*256+s, col=dir*2048+w*512+jg*32 + mi*16 + q*4
  const size_t xrowb = ((size_t)(16 * bg + l15) * 256) * (size_t)NN +
                       (size_t)dir * 2048 + w * 512 + jg * 32 + q * 4;

  // consumer mapping: thread t owns source chunk c_kt = t>>4, batch c_b = t&15,
  // units c_b*16 + p (p=0..15) -> hbuf row [c_kt][c_b][0..32)
  const int c_kt = t >> 4, c_b = t & 15;
  const int hdst = c_kt * 640 + c_b * 40;        // halves

#pragma unroll 1
  for (int st = 0; st < NS; st++) {
    const int s = dir ? (255 - st) : st;

    // prefetch xp (hides latency under the poll)
    const f16* xpp = xp + xrowb + (size_t)s * NN;
    uint2 xv0 = *(const uint2*)xpp;
    uint2 xv1 = *(const uint2*)(xpp + 16);
    cbar();

    if (st > 0) {
      // fused poll+load: retry until all 16 tags == st
      const u64* src = h_ex + ((size_t)((st & 1) * 8 + gid) * 16 + c_kt) * 256 + c_b * 16;
      u64 v[16];
      while (true) {
#pragma unroll
        for (int i = 0; i < 16; i++)
          v[i] = __hip_atomic_load(src + i, __ATOMIC_RELAXED, __HIP_MEMORY_SCOPE_SYSTEM);
        bool ok = true;
#pragma unroll
        for (int i = 0; i < 16; i++) ok &= ((u32)v[i] == (u32)st);
        if (ok) break;
      }
      // strip tags, write hbuf row (64B contiguous, 16B-aligned)
      uint4 d[4];
#pragma unroll
      for (int i = 0; i < 4; i++) {
        d[i].x = (u32)(v[4 * i + 0] >> 32);
        d[i].y = (u32)(v[4 * i + 1] >> 32);
        d[i].z = (u32)(v[4 * i + 2] >> 32);
        d[i].w = (u32)(v[4 * i + 3] >> 32);
      }
#pragma unroll
      for (int i = 0; i < 4; i++)
        *(uint4*)&hbuf[hdst + i * 8] = d[i];
    }
    __syncthreads();

    // z = w_hh @ h : 32 MFMAs/wave (skipped at st=0 where h==0)
    floatx4 acc0, acc1;
    acc0[0] = 0.f; acc0[1] = 0.f; acc0[2] = 0.f; acc0[3] = 0.f;
    acc1[0] = 0.f; acc1[1] = 0.f; acc1[2] = 0.f; acc1[3] = 0.f;
    if (st > 0) {
#pragma unroll
      for (int kt = 0; kt < 16; kt++) {
        half8 bf = *(const half8*)&hbuf[kt * 640 + l15 * 40 + q * 8];
        acc0 = __builtin_amdgcn_mfma_f32_16x16x32_f16(fa[0][kt], bf, acc0, 0, 0, 0);
        acc1 = __builtin_amdgcn_mfma_f32_16x16x32_f16(fa[1][kt], bf, acc1, 0, 0, 0);
      }
    }

    // z + xp -> LDS gate exchange (D layout: row=q*4+r, col=l15)
    {
      const f16* x0 = (const f16*)&xv0;
      const f16* x1 = (const f16*)&xv1;
#pragma unroll
      for (int r = 0; r < 4; r++) {
        zbuf[w][q * 4 + r][l15]      = acc0[r] + (float)x0[r];
        zbuf[w][16 + q * 4 + r][l15] = acc1[r] + (float)x1[r];
      }
    }
    __syncthreads();

    // LSTM cell update: 2 cells/thread, c persistent in VGPRs
#pragma unroll
    for (int i = 0; i < 2; i++) {
      int b = ub + i * 8;
      float iv = zbuf[0][uhu][b];
      float fv = zbuf[1][uhu][b];
      float gv = zbuf[2][uhu][b];
      float ov = zbuf[3][uhu][b];
      float ig = 1.f / (1.f + __expf(-iv));
      float fg = 1.f / (1.f + __expf(-fv));
      float og = 1.f / (1.f + __expf(-ov));
      creg[i] = fg * creg[i] + ig * tanhf(gv);
      hstage[b][uhu] = (f16)(og * tanhf(creg[i]));
    }
    __syncthreads();

    // publish: thread t stores unit (b=t>>4, p=t&15): [tag=st+1 | h_2p | h_2p+1]
    {
      const int pb = t >> 4, pp = t & 15;
      u32 pair = *(const u32*)&hstage[pb][2 * pp];
      u64 val = ((u64)pair << 32) | (u32)(st + 1);
      __hip_atomic_store(h_ex + ((size_t)(((st + 1) & 1) * 8 + gid) * 16 + jg) * 256 + t,
                         val, __ATOMIC_RELAXED, __HIP_MEMORY_SCOPE_SYSTEM);
      // h_seq for attention (off the critical path; k_attn is stream-ordered after)
      *(u32*)(h_seq + ((size_t)(16 * bg + pb) * 256 + s) * 1024 + dir * 512 + jg * 32 + 2 * pp) = pair;
    }
  }
}

// ---------------- attention pooling + lin1 + lin2 ----------------
__global__ __launch_bounds__(256) void k_attn(const f16* __restrict__ h_seq,
                                              const float* __restrict__ myw,
                                              const float* __restrict__ l1w,
                                              const float* __restrict__ l1b,
                                              const float* __restrict__ l2w,
                                              const float* __restrict__ l2b,
                                              float* __restrict__ out) {
  const int b = blockIdx.x;
  const int t = threadIdx.x;
  const int w = t >> 6, l = t & 63;
  float mw[16];
#pragma unroll
  for (int i = 0; i < 16; i += 4) {
    float4 v = *(const float4*)(myw + l * 16 + i);
    mw[i] = v.x; mw[i + 1] = v.y; mw[i + 2] = v.z; mw[i + 3] = v.w;
  }
  float pool[16];
#pragma unroll
  for (int i = 0; i < 16; i++) pool[i] = 0.f;
  float psum = 0.f;

  for (int s = w; s < NS; s += 4) {
    const f16* hp = h_seq + ((size_t)b * NS + s) * 1024 + l * 16;
    half8 h0 = *(const half8*)hp;
    half8 h1 = *(const half8*)(hp + 8);
    float hv[16];
#pragma unroll
    for (int i = 0; i < 8; i++) { hv[i] = (float)h0[i]; hv[8 + i] = (float)h1[i]; }
    float d = 0.f;
#pragma unroll
    for (int i = 0; i < 16; i++) d += hv[i] * mw[i];
#pragma unroll
    for (int off = 32; off > 0; off >>= 1) d += __shfl_xor(d, off);
    float p = __expf(tanhf(d));
    psum += p;
#pragma unroll
    for (int i = 0; i < 16; i++) pool[i] += p * hv[i];
  }

  __shared__ float zb[4][1024];
  __shared__ float ps[4];
  __shared__ float pooled[1024];
  __shared__ float h1s[512];
#pragma unroll
  for (int i = 0; i < 16; i++) zb[w][l * 16 + i] = pool[i];
  if (l == 0) ps[w] = psum;
  __syncthreads();
  float denom = ps[0] + ps[1] + ps[2] + ps[3];
  for (int d0 = t; d0 < 1024; d0 += 256)
    pooled[d0] = (zb[0][d0] + zb[1][d0] + zb[2][d0] + zb[3][d0]) / denom;
  __syncthreads();
  for (int r = t; r < 512; r += 256) {
    const float* wr = l1w + (size_t)r * 1024;
    float a = l1b[r];
    for (int k = 0; k < 1024; k += 4) {
      float4 wv = *(const float4*)(wr + k);
      a += wv.x * pooled[k] + wv.y * pooled[k + 1] + wv.z * pooled[k + 2] + wv.w * pooled[k + 3];
    }
    h1s[r] = a;
  }
  __syncthreads();
  if (t < 20) {
    const float* wr = l2w + t * 512;
    float a = l2b[t];
    for (int k = 0; k < 512; k++) a += h1s[k] * wr[k];
    out[b * 20 + t] = a;
  }
}

extern "C" void kernel_launch(void* const* d_in, const int* in_sizes, int n_in,
                              void* d_out, int out_size, void* d_ws, size_t ws_size,
                              hipStream_t stream) {
  (void)in_sizes; (void)n_in; (void)out_size; (void)ws_size;
  const int*   x     = (const int*)d_in[0];
  const float* embed = (const float*)d_in[1];
  const float* wihf  = (const float*)d_in[2];
  const float* whhf  = (const float*)d_in[3];
  const float* bihf  = (const float*)d_in[4];
  const float* bhhf  = (const float*)d_in[5];
  const float* wihb  = (const float*)d_in[6];
  const float* whhb  = (const float*)d_in[7];
  const float* bihb  = (const float*)d_in[8];
  const float* bhhb  = (const float*)d_in[9];
  const float* myw   = (const float*)d_in[10];
  const float* l1w   = (const float*)d_in[11];
  const float* l1b   = (const float*)d_in[12];
  const float* l2w   = (const float*)d_in[13];
  const float* l2b   = (const float*)d_in[14];

  char* ws = (char*)d_ws;
  f16*   xp    = (f16*)(ws + OFF_XP);
  f16*   emb_h = (f16*)(ws + OFF_EMB);
  u64*   h_ex  = (u64*)(ws + OFF_HEX);   // aliases emb_h (dead after k_gemm)
  f16*   w_cat = (f16*)(ws + OFF_WCAT);
  f16*   whh   = (f16*)(ws + OFF_WHH);
  f16*   h_seq = (f16*)(ws + OFF_HSEQ);
  float* bias  = (float*)(ws + OFF_BIAS);
  float* out   = (float*)d_out;

  k_prep<<<16, 256, 0, stream>>>(bias, bihf, bhhf, bihb, bhhb);
  k_embed<<<4096, 256, 0, stream>>>(x, embed, emb_h);
  k_wcast<<<2048, 256, 0, stream>>>(wihf, wihb, whhf, whhb, w_cat, whh);
  k_gemm<<<dim3(128, 32), 256, 0, stream>>>(emb_h, w_cat, bias, xp);
  k_rec<<<128, 256, 0, stream>>>(whh, xp, h_ex, h_seq);
  k_attn<<<64, 256, 0, stream>>>(h_seq, myw, l1w, l1b, l2w, l2b, out);
}

// Round 6
// 1422.239 us; speedup vs baseline: 1.1296x; 1.1296x over previous
//
#include <hip/hip_runtime.h>

typedef _Float16 f16;
typedef _Float16 half8 __attribute__((ext_vector_type(8)));
typedef float floatx4 __attribute__((ext_vector_type(4)));
typedef unsigned long long u64;
typedef unsigned int u32;

// Problem sizes
#define NB 64
#define NS 256
#define NE 512
#define NH 512
#define NG 2048   // 4H
#define NN 4096   // 2 dirs * 4H

// ---------------- workspace layout (bytes) ----------------
// xp     : f16 [16384][4096]   134217728   gate preacts (bias folded), both dirs
// emb_h  : f16 [16384][512]     16777216   (first 512KB reused as h_ex by k_rec)
// w_cat  : f16 [4096][512]       4194304   [w_ih_f ; w_ih_b]
// whh    : f16 [2][2048][512]    4194304
// h_seq  : f16 [64][256][1024]  33554432   [h_f | h_b] for attention
// h_ex   : u64 [2par][8gid][8jg][512u]     524288  tagged-h exchange (in emb_h region)
// bias   : f32 [4096]              16384
#define OFF_XP     0
#define OFF_EMB    134217728
#define OFF_HEX    134217728   // aliases emb_h: dead after k_gemm, k_rec is stream-ordered after
#define OFF_WCAT   150994944
#define OFF_WHH    155189248
#define OFF_HSEQ   159383552
#define OFF_BIAS   193200128

__device__ __forceinline__ void cbar() {  // compiler-only reorder barrier
  asm volatile("" ::: "memory");
}
__device__ __forceinline__ float sigf(float x) { return 1.f / (1.f + __expf(-x)); }
__device__ __forceinline__ float tanhfast(float x) {
  return 1.f - 2.f / (__expf(2.f * x) + 1.f);   // exact at +-inf, ~1e-7 rel err
}

// ---------------- prep: combine biases ----------------
__global__ void k_prep(float* bias, const float* bihf, const float* bhhf,
                       const float* bihb, const float* bhhb) {
  int id = blockIdx.x * 256 + threadIdx.x;       // 4096 threads
  bias[id] = (id < 2048) ? (bihf[id] + bhhf[id]) : (bihb[id - 2048] + bhhb[id - 2048]);
}

// ---------------- embedding gather + f32->f16 cast ----------------
__global__ void k_embed(const int* __restrict__ x, const float* __restrict__ embed,
                        f16* __restrict__ emb_h) {
  int gid = blockIdx.x * 256 + threadIdx.x;      // 1048576 threads, 8 halves each
  size_t base = (size_t)gid * 8;
  int r = (int)(base >> 9);
  int e = (int)(base & 511);
  int xi = x[r];
  const float4* src = (const float4*)(embed + (size_t)xi * 512 + e);
  float4 a = src[0], b = src[1];
  half8 h;
  h[0] = (f16)a.x; h[1] = (f16)a.y; h[2] = (f16)a.z; h[3] = (f16)a.w;
  h[4] = (f16)b.x; h[5] = (f16)b.y; h[6] = (f16)b.z; h[7] = (f16)b.w;
  *(half8*)(emb_h + base) = h;
}

// ---------------- weight casts ----------------
__global__ void k_wcast(const float* __restrict__ wihf, const float* __restrict__ wihb,
                        const float* __restrict__ whhf, const float* __restrict__ whhb,
                        f16* __restrict__ w_cat, f16* __restrict__ whh) {
  int gid = blockIdx.x * 256 + threadIdx.x;      // 524288 threads, 8 halves each
  size_t i8 = (size_t)gid * 8;
  const float* src;
  f16* dst;
  if (i8 < 2097152) {                            // w_cat [4096][512]
    size_t n = i8 >> 9, k = i8 & 511;
    src = (n < 2048 ? wihf + n * 512 : wihb + (n - 2048) * 512) + k;
    dst = w_cat + i8;
  } else {                                       // whh [2][2048][512]
    size_t i2 = i8 - 2097152;
    int dir = (int)(i2 >> 20);
    size_t rk = i2 & 1048575;
    src = (dir ? whhb : whhf) + rk;
    dst = whh + i2;
  }
  float4 a = *(const float4*)src, b = *(const float4*)(src + 4);
  half8 h;
  h[0] = (f16)a.x; h[1] = (f16)a.y; h[2] = (f16)a.z; h[3] = (f16)a.w;
  h[4] = (f16)b.x; h[5] = (f16)b.y; h[6] = (f16)b.z; h[7] = (f16)b.w;
  *(half8*)dst = h;
}

// ---------------- xproj GEMM: [16384,512] @ [4096,512]^T -> f16, +bias ----------
__global__ __launch_bounds__(256) void k_gemm(const f16* __restrict__ A,
                                              const f16* __restrict__ Bw,
                                              const float* __restrict__ bias,
                                              f16* __restrict__ xp) {
  __shared__ __align__(16) f16 As[128 * 32];
  __shared__ __align__(16) f16 Bs[128 * 32];
  const int t = threadIdx.x;
  const int m0 = blockIdx.x * 128;
  const int n0 = blockIdx.y * 128;
  const int w = t >> 6, l = t & 63;
  const int wm = w >> 1, wn = w & 1;
  const int l15 = l & 15, q8 = (l >> 4) * 8;

  floatx4 acc[4][4];
#pragma unroll
  for (int mi = 0; mi < 4; mi++)
#pragma unroll
    for (int ni = 0; ni < 4; ni++) {
      acc[mi][ni][0] = 0.f; acc[mi][ni][1] = 0.f;
      acc[mi][ni][2] = 0.f; acc[mi][ni][3] = 0.f;
    }

  for (int kt = 0; kt < 16; kt++) {
#pragma unroll
    for (int i = 0; i < 2; i++) {
      int c = t + 256 * i;
      int row = c >> 2, kc = (c & 3) * 8;
      *(uint4*)&As[row * 32 + kc] = *(const uint4*)(A + (size_t)(m0 + row) * 512 + kt * 32 + kc);
      *(uint4*)&Bs[row * 32 + kc] = *(const uint4*)(Bw + (size_t)(n0 + row) * 512 + kt * 32 + kc);
    }
    __syncthreads();
    half8 af[4], bf[4];
#pragma unroll
    for (int mi = 0; mi < 4; mi++)
      af[mi] = *(const half8*)&As[(wm * 64 + mi * 16 + l15) * 32 + q8];
#pragma unroll
    for (int ni = 0; ni < 4; ni++)
      bf[ni] = *(const half8*)&Bs[(wn * 64 + ni * 16 + l15) * 32 + q8];
#pragma unroll
    for (int mi = 0; mi < 4; mi++)
#pragma unroll
      for (int ni = 0; ni < 4; ni++)
        acc[mi][ni] = __builtin_amdgcn_mfma_f32_16x16x32_f16(af[mi], bf[ni], acc[mi][ni], 0, 0, 0);
    __syncthreads();
  }

#pragma unroll
  for (int ni = 0; ni < 4; ni++) {
    int ng = n0 + wn * 64 + ni * 16 + l15;
    float bv = bias[ng];
#pragma unroll
    for (int mi = 0; mi < 4; mi++) {
      int mg = m0 + wm * 64 + mi * 16 + (l >> 4) * 4;
#pragma unroll
      for (int r = 0; r < 4; r++)
        xp[(size_t)(mg + r) * 4096 + ng] = (f16)(acc[mi][ni][r] + bv);
    }
  }
}

// ---------------- recurrent kernel ----------------
// 64 blocks x 512 threads: blk = gid + 8*jg; gid = dir*4+bg (8 sync groups of 8
// blocks). Group handles 16 batches of one direction; block jg owns 64 hidden
// units; wave w owns (gate = w&3, hu-half = w>>2). w_hh rows in VGPRs (fa).
//
// Tagged u64 protocol (system-scope, flag-free, ack-free, deadlock-free):
// each u64 = [u32 payload = 2 f16 h | u32 tag = step+1]. Tag+data atomic per
// 8-byte store -> no release ack, no flag round trip. Producers fire-and-forget
// one u64/thread straight from cell-update registers (no LDS staging barrier).
// Consumers retry-load their 8 u64s (64 B line from ONE producer wave-store)
// until all tags match, with s_sleep backoff to limit IF spin traffic.
// 0xAA poison never matches tags 1..256; h_ex never read before written
// (st=0 skips the h-MFMA since h==0), so no init needed. Skew<=1 + double
// buffer (parity) makes overwrites safe.
__global__ __launch_bounds__(512, 2) void k_rec(const f16* __restrict__ whh,
                                                const f16* __restrict__ xp,
                                                u64* __restrict__ h_ex,
                                                f16* __restrict__ h_seq) {
  const int blk = blockIdx.x;
  const int gid = blk & 7;
  const int dir = gid >> 2, bg = gid & 3;
  const int jg  = blk >> 3;
  const int t = threadIdx.x;
  const int w = t >> 6, l = t & 63;
  const int l15 = l & 15, q = l >> 4;
  const int g = w & 3, hh = w >> 2;

  // A-frags: 32 w_hh rows per wave (2 m-tiles of 16), intended VGPR-resident
  half8 fa[2][16];
  {
    const f16* wb = whh + ((size_t)dir * 2048 + g * 512 + jg * 64 + hh * 32 + l15) * 512;
#pragma unroll
    for (int mi = 0; mi < 2; mi++)
#pragma unroll
      for (int kt = 0; kt < 16; kt++)
        fa[mi][kt] = *(const half8*)(wb + (size_t)mi * 16 * 512 + kt * 32 + q * 8);
  }

  __shared__ __align__(16) f16 hbuf[16 * 640];   // [kt16][b16][40]: conflict-free b128
  __shared__ float zbuf[4][64][17];              // [gate][hu_local][b16 pad17]

  float creg0 = 0.f, creg1 = 0.f;
  const int pb = t >> 5, pp = t & 31;            // cell/publish: batch pb, hu pair 2pp,2pp+1

  // xp: row=(16bg+l15)*256+s, col=dir*2048+g*512+jg*64+hh*32 + mi*16 + q*4
  const size_t xrowb = ((size_t)(16 * bg + l15) * 256) * (size_t)NN +
                       (size_t)dir * 2048 + g * 512 + jg * 64 + hh * 32 + q * 4;

  // consumer mapping: thread t loads 8 u64 from producer jgp = t>>6, T = t&63
  const int jgp = t >> 6, T = t & 63;
  const int c_b = T >> 2;                        // batch
  const int c_kt = jgp * 2 + ((T & 3) >> 1);     // k-chunk
  const int c_off = 16 * (T & 1);                // half-offset within chunk row
  const int hdst = c_kt * 640 + c_b * 40 + c_off;

  // publish slot & h_seq address (from cell registers, no staging)
  const size_t pubidx = (size_t)jg * 512 + t;
  f16* hseqb = h_seq + ((size_t)(16 * bg + pb) * 256) * 1024 + dir * 512 + jg * 64 + 2 * pp;

#pragma unroll 1
  for (int st = 0; st < NS; st++) {
    const int s = dir ? (255 - st) : st;

    // prefetch xp (hides latency under the poll)
    const f16* xpp = xp + xrowb + (size_t)s * NN;
    uint2 xv0 = *(const uint2*)xpp;
    uint2 xv1 = *(const uint2*)(xpp + 16);
    cbar();

    if (st > 0) {
      const u64* src = h_ex + ((size_t)((st & 1) * 8 + gid) * 8 + jgp) * 512 + T * 8;
      u64 v[8];
      while (true) {
#pragma unroll
        for (int i = 0; i < 8; i++)
          v[i] = __hip_atomic_load(src + i, __ATOMIC_RELAXED, __HIP_MEMORY_SCOPE_SYSTEM);
        bool ok = true;
#pragma unroll
        for (int i = 0; i < 8; i++) ok &= ((u32)v[i] == (u32)st);
        if (ok) break;
        __builtin_amdgcn_s_sleep(2);             // backoff: limit IF spin traffic
      }
      uint4 d0, d1;
      d0.x = (u32)(v[0] >> 32); d0.y = (u32)(v[1] >> 32);
      d0.z = (u32)(v[2] >> 32); d0.w = (u32)(v[3] >> 32);
      d1.x = (u32)(v[4] >> 32); d1.y = (u32)(v[5] >> 32);
      d1.z = (u32)(v[6] >> 32); d1.w = (u32)(v[7] >> 32);
      *(uint4*)&hbuf[hdst] = d0;
      *(uint4*)&hbuf[hdst + 8] = d1;
    }
    __syncthreads();

    // z = w_hh @ h : 32 MFMAs/wave (skipped at st=0 where h==0)
    floatx4 acc0, acc1;
    acc0[0] = 0.f; acc0[1] = 0.f; acc0[2] = 0.f; acc0[3] = 0.f;
    acc1[0] = 0.f; acc1[1] = 0.f; acc1[2] = 0.f; acc1[3] = 0.f;
    if (st > 0) {
#pragma unroll
      for (int kt = 0; kt < 16; kt++) {
        half8 bf = *(const half8*)&hbuf[kt * 640 + l15 * 40 + q * 8];
        acc0 = __builtin_amdgcn_mfma_f32_16x16x32_f16(fa[0][kt], bf, acc0, 0, 0, 0);
        acc1 = __builtin_amdgcn_mfma_f32_16x16x32_f16(fa[1][kt], bf, acc1, 0, 0, 0);
      }
    }

    // z + xp -> LDS gate exchange (D layout: row=q*4+r, col=l15)
    {
      const f16* x0 = (const f16*)&xv0;
      const f16* x1 = (const f16*)&xv1;
#pragma unroll
      for (int r = 0; r < 4; r++) {
        zbuf[g][hh * 32 + q * 4 + r][l15]      = acc0[r] + (float)x0[r];
        zbuf[g][hh * 32 + 16 + q * 4 + r][l15] = acc1[r] + (float)x1[r];
      }
    }
    __syncthreads();

    // LSTM cell update: 2 adjacent cells/thread, publish straight from registers
    {
      float i0 = zbuf[0][2 * pp][pb],     i1 = zbuf[0][2 * pp + 1][pb];
      float f0 = zbuf[1][2 * pp][pb],     f1 = zbuf[1][2 * pp + 1][pb];
      float g0 = zbuf[2][2 * pp][pb],     g1 = zbuf[2][2 * pp + 1][pb];
      float o0 = zbuf[3][2 * pp][pb],     o1 = zbuf[3][2 * pp + 1][pb];
      creg0 = sigf(f0) * creg0 + sigf(i0) * tanhfast(g0);
      creg1 = sigf(f1) * creg1 + sigf(i1) * tanhfast(g1);
      f16 hp[2];
      hp[0] = (f16)(sigf(o0) * tanhfast(creg0));
      hp[1] = (f16)(sigf(o1) * tanhfast(creg1));
      u32 pair = *(const u32*)hp;
      u64 val = ((u64)pair << 32) | (u32)(st + 1);
      __hip_atomic_store(h_ex + (size_t)(((st + 1) & 1) * 8 + gid) * 4096 + pubidx,
                         val, __ATOMIC_RELAXED, __HIP_MEMORY_SCOPE_SYSTEM);
      *(u32*)(hseqb + (size_t)s * 1024) = pair;  // attention input, off critical path
    }
  }
}

// ---------------- attention pooling + lin1 + lin2 ----------------
__global__ __launch_bounds__(256) void k_attn(const f16* __restrict__ h_seq,
                                              const float* __restrict__ myw,
                                              const float* __restrict__ l1w,
                                              const float* __restrict__ l1b,
                                              const float* __restrict__ l2w,
                                              const float* __restrict__ l2b,
                                              float* __restrict__ out) {
  const int b = blockIdx.x;
  const int t = threadIdx.x;
  const int w = t >> 6, l = t & 63;
  float mw[16];
#pragma unroll
  for (int i = 0; i < 16; i += 4) {
    float4 v = *(const float4*)(myw + l * 16 + i);
    mw[i] = v.x; mw[i + 1] = v.y; mw[i + 2] = v.z; mw[i + 3] = v.w;
  }
  float pool[16];
#pragma unroll
  for (int i = 0; i < 16; i++) pool[i] = 0.f;
  float psum = 0.f;

  for (int s = w; s < NS; s += 4) {
    const f16* hp = h_seq + ((size_t)b * NS + s) * 1024 + l * 16;
    half8 h0 = *(const half8*)hp;
    half8 h1 = *(const half8*)(hp + 8);
    float hv[16];
#pragma unroll
    for (int i = 0; i < 8; i++) { hv[i] = (float)h0[i]; hv[8 + i] = (float)h1[i]; }
    float d = 0.f;
#pragma unroll
    for (int i = 0; i < 16; i++) d += hv[i] * mw[i];
#pragma unroll
    for (int off = 32; off > 0; off >>= 1) d += __shfl_xor(d, off);
    float p = __expf(tanhf(d));
    psum += p;
#pragma unroll
    for (int i = 0; i < 16; i++) pool[i] += p * hv[i];
  }

  __shared__ float zb[4][1024];
  __shared__ float ps[4];
  __shared__ float pooled[1024];
  __shared__ float h1s[512];
#pragma unroll
  for (int i = 0; i < 16; i++) zb[w][l * 16 + i] = pool[i];
  if (l == 0) ps[w] = psum;
  __syncthreads();
  float denom = ps[0] + ps[1] + ps[2] + ps[3];
  for (int d0 = t; d0 < 1024; d0 += 256)
    pooled[d0] = (zb[0][d0] + zb[1][d0] + zb[2][d0] + zb[3][d0]) / denom;
  __syncthreads();
  for (int r = t; r < 512; r += 256) {
    const float* wr = l1w + (size_t)r * 1024;
    float a = l1b[r];
    for (int k = 0; k < 1024; k += 4) {
      float4 wv = *(const float4*)(wr + k);
      a += wv.x * pooled[k] + wv.y * pooled[k + 1] + wv.z * pooled[k + 2] + wv.w * pooled[k + 3];
    }
    h1s[r] = a;
  }
  __syncthreads();
  if (t < 20) {
    const float* wr = l2w + t * 512;
    float a = l2b[t];
    for (int k = 0; k < 512; k++) a += h1s[k] * wr[k];
    out[b * 20 + t] = a;
  }
}

extern "C" void kernel_launch(void* const* d_in, const int* in_sizes, int n_in,
                              void* d_out, int out_size, void* d_ws, size_t ws_size,
                              hipStream_t stream) {
  (void)in_sizes; (void)n_in; (void)out_size; (void)ws_size;
  const int*   x     = (const int*)d_in[0];
  const float* embed = (const float*)d_in[1];
  const float* wihf  = (const float*)d_in[2];
  const float* whhf  = (const float*)d_in[3];
  const float* bihf  = (const float*)d_in[4];
  const float* bhhf  = (const float*)d_in[5];
  const float* wihb  = (const float*)d_in[6];
  const float* whhb  = (const float*)d_in[7];
  const float* bihb  = (const float*)d_in[8];
  const float* bhhb  = (const float*)d_in[9];
  const float* myw   = (const float*)d_in[10];
  const float* l1w   = (const float*)d_in[11];
  const float* l1b   = (const float*)d_in[12];
  const float* l2w   = (const float*)d_in[13];
  const float* l2b   = (const float*)d_in[14];

  char* ws = (char*)d_ws;
  f16*   xp    = (f16*)(ws + OFF_XP);
  f16*   emb_h = (f16*)(ws + OFF_EMB);
  u64*   h_ex  = (u64*)(ws + OFF_HEX);   // aliases emb_h (dead after k_gemm)
  f16*   w_cat = (f16*)(ws + OFF_WCAT);
  f16*   whh   = (f16*)(ws + OFF_WHH);
  f16*   h_seq = (f16*)(ws + OFF_HSEQ);
  float* bias  = (float*)(ws + OFF_BIAS);
  float* out   = (float*)d_out;

  k_prep<<<16, 256, 0, stream>>>(bias, bihf, bhhf, bihb, bhhb);
  k_embed<<<4096, 256, 0, stream>>>(x, embed, emb_h);
  k_wcast<<<2048, 256, 0, stream>>>(wihf, wihb, whhf, whhb, w_cat, whh);
  k_gemm<<<dim3(128, 32), 256, 0, stream>>>(emb_h, w_cat, bias, xp);
  k_rec<<<64, 512, 0, stream>>>(whh, xp, h_ex, h_seq);
  k_attn<<<64, 256, 0, stream>>>(h_seq, myw, l1w, l1b, l2w, l2b, out);
}